// Round 1
// baseline (1042.896 us; speedup 1.0000x reference)
//
#include <hip/hip_runtime.h>
#include <hip/hip_bf16.h>
#include <math.h>

// ---------------------------------------------------------------------------
// MHA: out = softmax((q@Wq+bq)(k@Wk+bk)^T / sqrt(dk)) (v@Wv+bv) @ Wo + bo
// B=8 H=8 L=2048 D=128.  Pipeline:
//   cast(f32->bf16, W transposed, log2e/sqrt(128) folded into Wq/bq)
//   -> 3x MFMA GEMM proj (Qh/Kh [b][h][l][d], Vt [b][h][d][l])
//   -> flash attention (swapped QK^T, per-lane-q softmax, defer-max)
//   -> out-proj GEMM (f32 out + bo)
// Workspace: ~141 MB of d_ws.
// ---------------------------------------------------------------------------

typedef __attribute__((ext_vector_type(8))) short s16x8;   // 8 bf16
typedef __attribute__((ext_vector_type(4))) short s16x4;   // 4 bf16
typedef __attribute__((ext_vector_type(4))) float f32x4;

#define MFMA16(a, b, c) __builtin_amdgcn_mfma_f32_16x16x32_bf16((a), (b), (c), 0, 0, 0)

static constexpr int BN = 8, HN = 8, LN = 2048, DN = 128;
static constexpr int MROWS = BN * LN;   // 16384

static __device__ __forceinline__ unsigned short f2b(float f) {
  __hip_bfloat16 h = __float2bfloat16(f);
  union { __hip_bfloat16 h; unsigned short u; } cv;
  cv.h = h;
  return cv.u;
}

static __device__ __forceinline__ s16x8 ld16(const void* p) {
  uint4 t = *(const uint4*)p;
  return __builtin_bit_cast(s16x8, t);
}

// ---------------------------------------------------------------------------
// Kernel 1: casts + weight transposes.
// blocks [0,6144): q/k/v f32->bf16, 4 elems/thread (float4 in, 8B out)
// blocks [6144,8192): weight transposes Wt[n][k] = W[k][n] (bf16), Wq scaled.
// ---------------------------------------------------------------------------
__global__ __launch_bounds__(256) void cast_kernel(
    const float* __restrict__ q, const float* __restrict__ k,
    const float* __restrict__ v, const float* __restrict__ Wq,
    const float* __restrict__ Wk, const float* __restrict__ Wv,
    const float* __restrict__ Wo,
    __hip_bfloat16* __restrict__ qb, __hip_bfloat16* __restrict__ kb,
    __hip_bfloat16* __restrict__ vb, __hip_bfloat16* __restrict__ Wqt,
    __hip_bfloat16* __restrict__ Wkt, __hip_bfloat16* __restrict__ Wvt,
    __hip_bfloat16* __restrict__ Wot, float qscale)
{
  const int bid = blockIdx.x, tid = threadIdx.x;
  if (bid < 6144) {
    const int idx4 = bid * 256 + tid;           // [0, 1572864)
    const int arr  = idx4 >> 19;                // 524288 float4 per tensor
    const int off4 = idx4 & ((1 << 19) - 1);
    const float* src = (arr == 0) ? q : (arr == 1) ? k : v;
    __hip_bfloat16* dst = (arr == 0) ? qb : (arr == 1) ? kb : vb;
    float4 ld = ((const float4*)src)[off4];
    s16x4 pk;
    pk[0] = (short)f2b(ld.x); pk[1] = (short)f2b(ld.y);
    pk[2] = (short)f2b(ld.z); pk[3] = (short)f2b(ld.w);
    ((s16x4*)dst)[off4] = pk;
  } else {
    const int t = (bid - 6144) * 256 + tid;     // [0, 524288)
    const int which = t >> 17;                  // 131072 elems per weight
    const int i = t & ((1 << 17) - 1);
    if (which < 3) {
      const int n = i >> 7, kk = i & 127;       // Wt [1024][128]
      const float* W = (which == 0) ? Wq : (which == 1) ? Wk : Wv;
      __hip_bfloat16* Wt = (which == 0) ? Wqt : (which == 1) ? Wkt : Wvt;
      float val = W[kk * 1024 + n];
      if (which == 0) val *= qscale;            // fold log2e/sqrt(dk) into Q path
      Wt[n * 128 + kk] = __float2bfloat16(val);
    } else {
      const int n = i >> 10, kk = i & 1023;     // Wot [128][1024]
      Wot[n * 1024 + kk] = __float2bfloat16(Wo[kk * 128 + n]);
    }
  }
}

// ---------------------------------------------------------------------------
// Kernel 2: GEMM  C[M,N] = A[M,K] @ Btr[N,K]^T (+bias), 128x128 tile, BK=64,
// 4 waves (2x2), each 64x64 = 4x4 frags of 16x16x32 bf16 MFMA.
// LDS rows 128B, XOR-swizzled on the *source* side (linear LDS dest).
// MODE 0: out bf16 [b][h][l][d]   (Q/K projections; bias*bias_scale)
// MODE 2: out bf16 [b][h][d][l]   (V projection, transposed for PV)
// MODE 3: out f32  [M][128]       (final projection + bo)
// ---------------------------------------------------------------------------
template <int MODE>
__global__ __launch_bounds__(256) void gemm_kernel(
    const __hip_bfloat16* __restrict__ A, const __hip_bfloat16* __restrict__ Btr,
    const float* __restrict__ bias, void* __restrict__ outp,
    int K, float bias_scale)
{
  __shared__ uint4 lds4[2048];                  // 32 KB
  char* As = (char*)lds4;                       // [128][64] bf16 (swizzled)
  char* Bs = As + 16384;                        // [128][64] bf16 (swizzled)

  const int tid = threadIdx.x;
  const int l = tid & 63, w = tid >> 6;
  const int wr = w >> 1, wc = w & 1;
  const int m0 = blockIdx.x * 128, n0 = blockIdx.y * 128;
  const int cq = l & 15, rg = l >> 4;

  f32x4 acc[4][4] = {};

  const int lrow8 = l >> 3, lcol8 = l & 7;
  const int swzoff = ((lcol8 ^ lrow8) * 8);     // element offset (16B units xor'd)
  const int nk = K >> 6;

  for (int kt = 0; kt < nk; ++kt) {
    const int k0 = kt << 6;
    uint4 ra[4], rb[4];
#pragma unroll
    for (int c = 0; c < 4; ++c) {
      const int ca = w * 4 + c;
      const int row = ca * 8 + lrow8;
      ra[c] = *(const uint4*)(A   + (size_t)(m0 + row) * K + k0 + swzoff);
      rb[c] = *(const uint4*)(Btr + (size_t)(n0 + row) * K + k0 + swzoff);
    }
    __syncthreads();   // previous iter's reads done before overwrite
#pragma unroll
    for (int c = 0; c < 4; ++c) {
      const int ca = w * 4 + c;
      *(uint4*)(As + ca * 1024 + l * 16) = ra[c];
      *(uint4*)(Bs + ca * 1024 + l * 16) = rb[c];
    }
    __syncthreads();
#pragma unroll
    for (int ks = 0; ks < 2; ++ks) {
      s16x8 af[4], bf[4];
#pragma unroll
      for (int mf = 0; mf < 4; ++mf) {
        const int arow = wr * 64 + mf * 16 + cq;
        af[mf] = ld16(As + arow * 128 + ((ks * 64 + rg * 16) ^ ((arow & 7) << 4)));
      }
#pragma unroll
      for (int nf = 0; nf < 4; ++nf) {
        const int brow = wc * 64 + nf * 16 + cq;
        bf[nf] = ld16(Bs + brow * 128 + ((ks * 64 + rg * 16) ^ ((brow & 7) << 4)));
      }
#pragma unroll
      for (int mf = 0; mf < 4; ++mf)
#pragma unroll
        for (int nf = 0; nf < 4; ++nf)
          acc[mf][nf] = MFMA16(af[mf], bf[nf], acc[mf][nf]);
    }
  }

  // epilogue: C/D layout col = lane&15, row = (lane>>4)*4 + r   [m89/m91]
#pragma unroll
  for (int nf = 0; nf < 4; ++nf) {
    const int gn = n0 + wc * 64 + nf * 16 + cq;
    const float bv = bias[gn] * bias_scale;
#pragma unroll
    for (int mf = 0; mf < 4; ++mf) {
      const int gm0 = m0 + wr * 64 + mf * 16 + rg * 4;
      const f32x4 a = acc[mf][nf];
      if (MODE == 0) {
        const int h = gn >> 7, d = gn & 127;
        __hip_bfloat16* o = (__hip_bfloat16*)outp;
#pragma unroll
        for (int r = 0; r < 4; ++r) {
          const int gm = gm0 + r;
          const int b = gm >> 11, lr = gm & (LN - 1);
          o[((size_t)(b * HN + h) * LN + lr) * 128 + d] = __float2bfloat16(a[r] + bv);
        }
      } else if (MODE == 2) {
        const int h = gn >> 7, d = gn & 127;
        const int b = gm0 >> 11, kv = gm0 & (LN - 1);
        s16x4 pk;
#pragma unroll
        for (int r = 0; r < 4; ++r) pk[r] = (short)f2b(a[r] + bv);
        *(s16x4*)((__hip_bfloat16*)outp + ((size_t)(b * HN + h) * 128 + d) * LN + kv) = pk;
      } else {
        float* o = (float*)outp;   // N == 128
#pragma unroll
        for (int r = 0; r < 4; ++r)
          o[(size_t)(gm0 + r) * 128 + gn] = a[r] + bv;
      }
    }
  }
}

// ---------------------------------------------------------------------------
// Kernel 3: flash attention. One block = one (b,h) x 64 q-rows; 4 waves x 16 q.
// Swapped QK^T: S^T = mfma(K_tile, Q^T) -> lane owns col q = lane&15.
//   softmax reduce = shfl_xor(16/32); O^T accumulated (V^T row-contiguous).
// P goes through 1KB/wave swizzled LDS to become PV's B-operand.
// Scores arrive pre-scaled by log2e/sqrt(dk) -> pure exp2 softmax.
// ---------------------------------------------------------------------------
__global__ __launch_bounds__(256) void attn_kernel(
    const __hip_bfloat16* __restrict__ Qh, const __hip_bfloat16* __restrict__ Kh,
    const __hip_bfloat16* __restrict__ Vt, __hip_bfloat16* __restrict__ Obuf)
{
  __shared__ uint4 smem4[(4096 + 16384) / 16];
  char* Pl = (char*)smem4;            // 4 KB:  [wave][16 q][32 kv] bf16 swz
  char* Ot = (char*)smem4 + 4096;     // 16 KB: [wave][16 q][128 d] bf16 swz

  // bijective XCD swizzle: all 32 q-tiles of a head land on one XCD
  const int x = blockIdx.x;
  const int xcd = x & 7, j = x >> 3;
  const int bh = xcd * 8 + (j >> 5);  // [0,64)
  const int qt = j & 31;

  const int tid = threadIdx.x, l = tid & 63, w = tid >> 6;
  const int cq = l & 15, rg = l >> 4;
  const int q0 = qt * 64 + w * 16;

  const __hip_bfloat16* Qp = Qh + (size_t)bh * LN * 128;
  const __hip_bfloat16* Kp = Kh + (size_t)bh * LN * 128;
  const __hip_bfloat16* Vp = Vt + (size_t)bh * 128 * LN;

  // Q as B-operand: lane reads row (q0+cq), k-chunk rg*8  (held in regs)
  s16x8 qf[4];
#pragma unroll
  for (int ks = 0; ks < 4; ++ks)
    qf[ks] = ld16(Qp + (size_t)(q0 + cq) * 128 + ks * 32 + rg * 8);

  f32x4 acc[8] = {};                  // O^T: 8 d-frags x (4 d-rows, col q)
  float m = -INFINITY, lsum = 0.f;

  char* Plw = Pl + w * 1024;
  const char* prd = Plw + cq * 64 + ((rg * 16) ^ ((cq & 3) << 4));

#pragma unroll 2
  for (int kv0 = 0; kv0 < LN; kv0 += 32) {
    // S^T (2 frags: kv 0-15, 16-31)
    f32x4 st0 = {}, st1 = {};
#pragma unroll
    for (int ks = 0; ks < 4; ++ks) {
      s16x8 kf0 = ld16(Kp + (size_t)(kv0 + cq) * 128 + ks * 32 + rg * 8);
      s16x8 kf1 = ld16(Kp + (size_t)(kv0 + 16 + cq) * 128 + ks * 32 + rg * 8);
      st0 = MFMA16(kf0, qf[ks], st0);
      st1 = MFMA16(kf1, qf[ks], st1);
    }
    // online softmax in log2 domain; lane's 8 values are kv-slots of its q
    float pmax = fmaxf(fmaxf(fmaxf(st0[0], st0[1]), fmaxf(st0[2], st0[3])),
                       fmaxf(fmaxf(st1[0], st1[1]), fmaxf(st1[2], st1[3])));
    pmax = fmaxf(pmax, __shfl_xor(pmax, 16));
    pmax = fmaxf(pmax, __shfl_xor(pmax, 32));
    if (!__all(pmax <= m + 8.0f)) {   // defer-max (T13), THR=8 log2-units
      const float mn = fmaxf(m, pmax);
      const float sc = exp2f(m - mn);
      m = mn;
      lsum *= sc;
#pragma unroll
      for (int f = 0; f < 8; ++f) {
        acc[f][0] *= sc; acc[f][1] *= sc; acc[f][2] *= sc; acc[f][3] *= sc;
      }
    }
    float p0 = exp2f(st0[0] - m), p1 = exp2f(st0[1] - m);
    float p2 = exp2f(st0[2] - m), p3 = exp2f(st0[3] - m);
    float p4 = exp2f(st1[0] - m), p5 = exp2f(st1[1] - m);
    float p6 = exp2f(st1[2] - m), p7 = exp2f(st1[3] - m);
    lsum += ((p0 + p1) + (p2 + p3)) + ((p4 + p5) + (p6 + p7));

    s16x4 pk0, pk1;
    pk0[0] = (short)f2b(p0); pk0[1] = (short)f2b(p1);
    pk0[2] = (short)f2b(p2); pk0[3] = (short)f2b(p3);
    pk1[0] = (short)f2b(p4); pk1[1] = (short)f2b(p5);
    pk1[2] = (short)f2b(p6); pk1[3] = (short)f2b(p7);
    *(s16x4*)(Plw + cq * 64 + ((rg * 8) ^ ((cq & 3) << 4))) = pk0;
    *(s16x4*)(Plw + cq * 64 + ((32 + rg * 8) ^ ((cq & 3) << 4))) = pk1;

    const s16x8 pb = ld16(prd);       // P^T B-operand (wave-local, lgkmcnt by compiler)
#pragma unroll
    for (int fd = 0; fd < 8; ++fd) {
      s16x8 va = ld16(Vp + (size_t)(fd * 16 + cq) * LN + kv0 + rg * 8);
      acc[fd] = MFMA16(va, pb, acc[fd]);
    }
  }

  lsum += __shfl_xor(lsum, 16);
  lsum += __shfl_xor(lsum, 32);
  const float rinv = 1.0f / lsum;

  // O^T -> swizzled LDS -> coalesced rows of Obuf [16384][1024] bf16
  char* Otw = Ot + w * 4096;
#pragma unroll
  for (int fd = 0; fd < 8; ++fd) {
#pragma unroll
    for (int rr = 0; rr < 4; rr += 2) {
      const unsigned int pk = (unsigned)f2b(acc[fd][rr] * rinv) |
                              ((unsigned)f2b(acc[fd][rr + 1] * rinv) << 16);
      const int d0 = fd * 16 + rg * 4 + rr;
      *(unsigned int*)(Otw + cq * 256 + ((d0 * 2) ^ ((cq & 7) << 4))) = pk;
    }
  }
  const int b = bh >> 3, h = bh & 7;
#pragma unroll
  for (int pr = 0; pr < 4; ++pr) {
    const int ql = pr * 4 + rg;
    uint4 vld = *(const uint4*)(Otw + ql * 256 + ((cq * 16) ^ ((ql & 7) << 4)));
    *(uint4*)((char*)Obuf + ((size_t)(b * LN + q0 + ql) * 1024 + h * 128) * 2 + cq * 16) = vld;
  }
}

// ---------------------------------------------------------------------------
extern "C" void kernel_launch(void* const* d_in, const int* in_sizes, int n_in,
                              void* d_out, int out_size, void* d_ws, size_t ws_size,
                              hipStream_t stream)
{
  (void)in_sizes; (void)n_in; (void)out_size; (void)ws_size;
  const float* q  = (const float*)d_in[0];
  const float* k  = (const float*)d_in[1];
  const float* v  = (const float*)d_in[2];
  const float* Wq = (const float*)d_in[3];
  const float* bq = (const float*)d_in[4];
  const float* Wk = (const float*)d_in[5];
  const float* bk = (const float*)d_in[6];
  const float* Wv = (const float*)d_in[7];
  const float* bv = (const float*)d_in[8];
  const float* Wo = (const float*)d_in[9];
  const float* bo = (const float*)d_in[10];

  char* ws = (char*)d_ws;
  size_t off = 0;
  auto alloc = [&](size_t bytes) { char* p = ws + off; off += (bytes + 255) & ~(size_t)255; return p; };
  __hip_bfloat16* qb  = (__hip_bfloat16*)alloc((size_t)MROWS * 128 * 2);       // 4 MB
  __hip_bfloat16* kb  = (__hip_bfloat16*)alloc((size_t)MROWS * 128 * 2);
  __hip_bfloat16* vb  = (__hip_bfloat16*)alloc((size_t)MROWS * 128 * 2);
  __hip_bfloat16* Wqt = (__hip_bfloat16*)alloc(1024 * 128 * 2);
  __hip_bfloat16* Wkt = (__hip_bfloat16*)alloc(1024 * 128 * 2);
  __hip_bfloat16* Wvt = (__hip_bfloat16*)alloc(1024 * 128 * 2);
  __hip_bfloat16* Wot = (__hip_bfloat16*)alloc(128 * 1024 * 2);
  __hip_bfloat16* Qh  = (__hip_bfloat16*)alloc((size_t)64 * LN * 128 * 2);     // 32 MB
  __hip_bfloat16* Kh  = (__hip_bfloat16*)alloc((size_t)64 * LN * 128 * 2);
  __hip_bfloat16* Vt  = (__hip_bfloat16*)alloc((size_t)64 * LN * 128 * 2);
  __hip_bfloat16* Ob  = (__hip_bfloat16*)alloc((size_t)MROWS * 1024 * 2);      // 32 MB
  // total ~141 MB

  const float qscale = 1.4426950408889634f / sqrtf(128.0f);  // log2(e)/sqrt(dk)

  cast_kernel<<<8192, 256, 0, stream>>>(q, k, v, Wq, Wk, Wv, Wo,
                                        qb, kb, vb, Wqt, Wkt, Wvt, Wot, qscale);
  gemm_kernel<0><<<dim3(128, 8), 256, 0, stream>>>(qb, Wqt, bq, Qh, 128, qscale);
  gemm_kernel<0><<<dim3(128, 8), 256, 0, stream>>>(kb, Wkt, bk, Kh, 128, 1.0f);
  gemm_kernel<2><<<dim3(128, 8), 256, 0, stream>>>(vb, Wvt, bv, Vt, 128, 1.0f);
  attn_kernel<<<2048, 256, 0, stream>>>(Qh, Kh, Vt, Ob);
  gemm_kernel<3><<<dim3(128, 1), 256, 0, stream>>>(Ob, Wot, bo, d_out, 1024, 1.0f);
}

// Round 2
// 321.851 us; speedup vs baseline: 3.2403x; 3.2403x over previous
//
#include <hip/hip_runtime.h>
#include <hip/hip_bf16.h>
#include <math.h>

// ---------------------------------------------------------------------------
// MHA: out = softmax((q@Wq+bq)(k@Wk+bk)^T / sqrt(dk)) (v@Wv+bv) @ Wo + bo
// B=8 H=8 L=2048 D=128.  Pipeline:
//   cast(f32->bf16, W transposed, log2e/sqrt(128) folded into Wq/bq)
//   -> 3x MFMA GEMM proj (Qh/Kh [b][h][l][d], Vt [b][h][d][l])
//   -> flash attention v2: 8 waves x 32q, KVBLK=64, K/V LDS dbuf (T14 split),
//      XOR-swizzled LDS, swapped QK^T, per-lane-q softmax, defer-max
//   -> out-proj GEMM (f32 out + bo)
// ---------------------------------------------------------------------------

typedef __attribute__((ext_vector_type(8))) short s16x8;   // 8 bf16
typedef __attribute__((ext_vector_type(4))) short s16x4;   // 4 bf16
typedef __attribute__((ext_vector_type(4))) float f32x4;

#define MFMA16(a, b, c) __builtin_amdgcn_mfma_f32_16x16x32_bf16((a), (b), (c), 0, 0, 0)

static constexpr int BN = 8, HN = 8, LN = 2048, DN = 128;
static constexpr int MROWS = BN * LN;   // 16384

static __device__ __forceinline__ unsigned short f2b(float f) {
  __hip_bfloat16 h = __float2bfloat16(f);
  union { __hip_bfloat16 h; unsigned short u; } cv;
  cv.h = h;
  return cv.u;
}

static __device__ __forceinline__ s16x8 ld16(const void* p) {
  uint4 t = *(const uint4*)p;
  return __builtin_bit_cast(s16x8, t);
}

// ---------------------------------------------------------------------------
// Kernel 1: casts + weight transposes (unchanged from r1).
// ---------------------------------------------------------------------------
__global__ __launch_bounds__(256) void cast_kernel(
    const float* __restrict__ q, const float* __restrict__ k,
    const float* __restrict__ v, const float* __restrict__ Wq,
    const float* __restrict__ Wk, const float* __restrict__ Wv,
    const float* __restrict__ Wo,
    __hip_bfloat16* __restrict__ qb, __hip_bfloat16* __restrict__ kb,
    __hip_bfloat16* __restrict__ vb, __hip_bfloat16* __restrict__ Wqt,
    __hip_bfloat16* __restrict__ Wkt, __hip_bfloat16* __restrict__ Wvt,
    __hip_bfloat16* __restrict__ Wot, float qscale)
{
  const int bid = blockIdx.x, tid = threadIdx.x;
  if (bid < 6144) {
    const int idx4 = bid * 256 + tid;
    const int arr  = idx4 >> 19;
    const int off4 = idx4 & ((1 << 19) - 1);
    const float* src = (arr == 0) ? q : (arr == 1) ? k : v;
    __hip_bfloat16* dst = (arr == 0) ? qb : (arr == 1) ? kb : vb;
    float4 ld = ((const float4*)src)[off4];
    s16x4 pk;
    pk[0] = (short)f2b(ld.x); pk[1] = (short)f2b(ld.y);
    pk[2] = (short)f2b(ld.z); pk[3] = (short)f2b(ld.w);
    ((s16x4*)dst)[off4] = pk;
  } else {
    const int t = (bid - 6144) * 256 + tid;
    const int which = t >> 17;
    const int i = t & ((1 << 17) - 1);
    if (which < 3) {
      const int n = i >> 7, kk = i & 127;
      const float* W = (which == 0) ? Wq : (which == 1) ? Wk : Wv;
      __hip_bfloat16* Wt = (which == 0) ? Wqt : (which == 1) ? Wkt : Wvt;
      float val = W[kk * 1024 + n];
      if (which == 0) val *= qscale;
      Wt[n * 128 + kk] = __float2bfloat16(val);
    } else {
      const int n = i >> 10, kk = i & 1023;
      Wot[n * 1024 + kk] = __float2bfloat16(Wo[kk * 128 + n]);
    }
  }
}

// ---------------------------------------------------------------------------
// Kernel 2: GEMM (unchanged from r1).  C[M,N] = A[M,K] @ Btr[N,K]^T (+bias)
// ---------------------------------------------------------------------------
template <int MODE>
__global__ __launch_bounds__(256) void gemm_kernel(
    const __hip_bfloat16* __restrict__ A, const __hip_bfloat16* __restrict__ Btr,
    const float* __restrict__ bias, void* __restrict__ outp,
    int K, float bias_scale)
{
  __shared__ uint4 lds4[2048];                  // 32 KB
  char* As = (char*)lds4;
  char* Bs = As + 16384;

  const int tid = threadIdx.x;
  const int l = tid & 63, w = tid >> 6;
  const int wr = w >> 1, wc = w & 1;
  const int m0 = blockIdx.x * 128, n0 = blockIdx.y * 128;
  const int cq = l & 15, rg = l >> 4;

  f32x4 acc[4][4] = {};

  const int lrow8 = l >> 3, lcol8 = l & 7;
  const int swzoff = ((lcol8 ^ lrow8) * 8);
  const int nk = K >> 6;

  for (int kt = 0; kt < nk; ++kt) {
    const int k0 = kt << 6;
    uint4 ra[4], rb[4];
#pragma unroll
    for (int c = 0; c < 4; ++c) {
      const int ca = w * 4 + c;
      const int row = ca * 8 + lrow8;
      ra[c] = *(const uint4*)(A   + (size_t)(m0 + row) * K + k0 + swzoff);
      rb[c] = *(const uint4*)(Btr + (size_t)(n0 + row) * K + k0 + swzoff);
    }
    __syncthreads();
#pragma unroll
    for (int c = 0; c < 4; ++c) {
      const int ca = w * 4 + c;
      *(uint4*)(As + ca * 1024 + l * 16) = ra[c];
      *(uint4*)(Bs + ca * 1024 + l * 16) = rb[c];
    }
    __syncthreads();
#pragma unroll
    for (int ks = 0; ks < 2; ++ks) {
      s16x8 af[4], bf[4];
#pragma unroll
      for (int mf = 0; mf < 4; ++mf) {
        const int arow = wr * 64 + mf * 16 + cq;
        af[mf] = ld16(As + arow * 128 + ((ks * 64 + rg * 16) ^ ((arow & 7) << 4)));
      }
#pragma unroll
      for (int nf = 0; nf < 4; ++nf) {
        const int brow = wc * 64 + nf * 16 + cq;
        bf[nf] = ld16(Bs + brow * 128 + ((ks * 64 + rg * 16) ^ ((brow & 7) << 4)));
      }
#pragma unroll
      for (int mf = 0; mf < 4; ++mf)
#pragma unroll
        for (int nf = 0; nf < 4; ++nf)
          acc[mf][nf] = MFMA16(af[mf], bf[nf], acc[mf][nf]);
    }
  }

#pragma unroll
  for (int nf = 0; nf < 4; ++nf) {
    const int gn = n0 + wc * 64 + nf * 16 + cq;
    const float bv = bias[gn] * bias_scale;
#pragma unroll
    for (int mf = 0; mf < 4; ++mf) {
      const int gm0 = m0 + wr * 64 + mf * 16 + rg * 4;
      const f32x4 a = acc[mf][nf];
      if (MODE == 0) {
        const int h = gn >> 7, d = gn & 127;
        __hip_bfloat16* o = (__hip_bfloat16*)outp;
#pragma unroll
        for (int r = 0; r < 4; ++r) {
          const int gm = gm0 + r;
          const int b = gm >> 11, lr = gm & (LN - 1);
          o[((size_t)(b * HN + h) * LN + lr) * 128 + d] = __float2bfloat16(a[r] + bv);
        }
      } else if (MODE == 2) {
        const int h = gn >> 7, d = gn & 127;
        const int b = gm0 >> 11, kv = gm0 & (LN - 1);
        s16x4 pk;
#pragma unroll
        for (int r = 0; r < 4; ++r) pk[r] = (short)f2b(a[r] + bv);
        *(s16x4*)((__hip_bfloat16*)outp + ((size_t)(b * HN + h) * 128 + d) * LN + kv) = pk;
      } else {
        float* o = (float*)outp;
#pragma unroll
        for (int r = 0; r < 4; ++r)
          o[(size_t)(gm0 + r) * 128 + gn] = a[r] + bv;
      }
    }
  }
}

// ---------------------------------------------------------------------------
// Kernel 3: flash attention v2.
// Block = 8 waves (512 thr) = 256 q-rows of one (b,h). Wave: 32 q (2 frags).
// KVBLK=64.  K tile [64][128] + V^T tile [128][64] in LDS, double-buffered,
// reg-staged (T14: issue loads at iter top, ds_write after compute).
// All LDS addrs XOR-swizzled byte ^= ((row&7)<<4)  -> <=2-way conflicts.
// Swapped QK^T: S^T = mfma(K, Q^T), lane owns q = lane&15; softmax per-lane
// + shfl_xor(16,32); defer-max (THR=8 log2 units); P via 2KB wave-local LDS.
// LDS: K 2x16K | V 2x16K | P 8x2K = 80 KB -> 1 block/CU, 2 waves/SIMD.
// ---------------------------------------------------------------------------
__global__ __launch_bounds__(512, 2) void attn_kernel(
    const __hip_bfloat16* __restrict__ Qh, const __hip_bfloat16* __restrict__ Kh,
    const __hip_bfloat16* __restrict__ Vt, __hip_bfloat16* __restrict__ Obuf)
{
  __shared__ char lds[81920];          // 80 KB
  char* Ks = lds;                      // [2][64 rows][256B]  (swz)
  char* Vs = lds + 32768;              // [2][128 rows][128B] (swz)

  // bijective XCD swizzle: 512 blocks = 8 xcd x 8 bh x 8 qtiles
  const int x = blockIdx.x;
  const int xcd = x & 7, i = x >> 3;
  const int bh = xcd * 8 + (i >> 3);
  const int qt = i & 7;

  const int tid = threadIdx.x, l = tid & 63, w = tid >> 6;   // w in [0,8)
  const int cq = l & 15, rg = l >> 4;
  const int q0 = qt * 256 + w * 32;

  char* Pw = lds + 65536 + w * 2048;   // per-wave P: [16 q][128B] (swz)

  const char* Qc = (const char*)(Qh + (size_t)bh * LN * 128);
  const char* Kc = (const char*)(Kh + (size_t)bh * LN * 128);
  const char* Vc = (const char*)(Vt + (size_t)bh * 128 * LN);

  // Q fragments in registers: qreg[qf][ks] (B-operand of swapped QK^T)
  s16x8 qreg[2][4];
#pragma unroll
  for (int qf = 0; qf < 2; ++qf)
#pragma unroll
    for (int ks = 0; ks < 4; ++ks)
      qreg[qf][ks] = ld16(Qc + (size_t)(q0 + qf * 16 + cq) * 256 + ks * 64 + rg * 16);

  // staging geometry (per thread, 2 chunks K + 2 chunks V per tile)
  // K tile: 1024 chunks of 16B; chunk c: row=c>>4 (256B rows), col16=c&15
  // V tile: 1024 chunks;       chunk c: row=c>>3 (128B rows), col16=c&7
  int kth[2], kds[2], vth[2], vds[2];
#pragma unroll
  for (int j = 0; j < 2; ++j) {
    const int ck = w * 128 + j * 64 + l;
    const int kr = ck >> 4, kc = ck & 15;
    kth[j] = kr * 256 + kc * 16;                       // global byte offset (linear)
    kds[j] = kr * 256 + ((kc * 16) ^ ((kr & 7) << 4)); // LDS byte offset (swz)
    const int vr = ck >> 3, vc = ck & 7;
    vth[j] = vr * 4096 + vc * 16;                      // global: row stride LN*2
    vds[j] = vr * 128 + ((vc * 16) ^ ((vr & 7) << 4));
  }

  f32x4 acc[8][2] = {};
  float m0 = -INFINITY, m1 = -INFINITY, ls0 = 0.f, ls1 = 0.f;

  // prologue: stage tile 0 -> buf 0
  {
#pragma unroll
    for (int j = 0; j < 2; ++j) {
      uint4 a = *(const uint4*)(Kc + kth[j]);
      uint4 b = *(const uint4*)(Vc + vth[j]);
      *(uint4*)(Ks + kds[j]) = a;
      *(uint4*)(Vs + vds[j]) = b;
    }
  }
  __syncthreads();

  for (int t = 0; t < 32; ++t) {
    const int cur = t & 1;
    char* Kb = Ks + cur * 16384;
    char* Vb = Vs + cur * 16384;

    // T14 issue-early: global loads for tile t+1
    uint4 sk[2], sv[2];
    if (t < 31) {
      const char* kg = Kc + (size_t)(t + 1) * 16384;   // kv0*256B
      const char* vg = Vc + (size_t)(t + 1) * 128;     // kv0*2B
#pragma unroll
      for (int j = 0; j < 2; ++j) {
        sk[j] = *(const uint4*)(kg + kth[j]);
        sv[j] = *(const uint4*)(vg + vth[j]);
      }
    }

    // QK^T: S^T frags st[qf][t4]  (kv = t4*16 + rg*4 + r, q = qf*16 + cq)
    f32x4 st[2][4] = {};
#pragma unroll
    for (int t4 = 0; t4 < 4; ++t4) {
      const int row = t4 * 16 + cq;
      s16x8 kf[4];
#pragma unroll
      for (int ks = 0; ks < 4; ++ks)
        kf[ks] = ld16(Kb + row * 256 + ((ks * 64 + rg * 16) ^ ((row & 7) << 4)));
#pragma unroll
      for (int ks = 0; ks < 4; ++ks) {
        st[0][t4] = MFMA16(kf[ks], qreg[0][ks], st[0][t4]);
        st[1][t4] = MFMA16(kf[ks], qreg[1][ks], st[1][t4]);
      }
    }

    // online softmax (log2 domain), defer-max THR=8
    float pm0 = st[0][0][0], pm1 = st[1][0][0];
#pragma unroll
    for (int t4 = 0; t4 < 4; ++t4)
#pragma unroll
      for (int r = 0; r < 4; ++r) {
        pm0 = fmaxf(pm0, st[0][t4][r]);
        pm1 = fmaxf(pm1, st[1][t4][r]);
      }
    pm0 = fmaxf(pm0, __shfl_xor(pm0, 16)); pm0 = fmaxf(pm0, __shfl_xor(pm0, 32));
    pm1 = fmaxf(pm1, __shfl_xor(pm1, 16)); pm1 = fmaxf(pm1, __shfl_xor(pm1, 32));
    if (__any((pm0 > m0 + 8.0f) || (pm1 > m1 + 8.0f))) {
      const float n0 = fmaxf(m0, pm0), n1 = fmaxf(m1, pm1);
      const float sc0 = exp2f(m0 - n0), sc1 = exp2f(m1 - n1);
      m0 = n0; m1 = n1; ls0 *= sc0; ls1 *= sc1;
#pragma unroll
      for (int fd = 0; fd < 8; ++fd)
#pragma unroll
        for (int r = 0; r < 4; ++r) {
          acc[fd][0][r] *= sc0;
          acc[fd][1][r] *= sc1;
        }
    }

    // P = exp2(S - m), pack bf16, through wave-local swizzled LDS
    s16x8 pb[2][2];
#pragma unroll
    for (int qf = 0; qf < 2; ++qf) {
      const float mm = qf ? m1 : m0;
      float sum = 0.f;
#pragma unroll
      for (int t4 = 0; t4 < 4; ++t4) {
        float e0 = exp2f(st[qf][t4][0] - mm);
        float e1 = exp2f(st[qf][t4][1] - mm);
        float e2 = exp2f(st[qf][t4][2] - mm);
        float e3 = exp2f(st[qf][t4][3] - mm);
        sum += (e0 + e1) + (e2 + e3);
        s16x4 pk;
        pk[0] = (short)f2b(e0); pk[1] = (short)f2b(e1);
        pk[2] = (short)f2b(e2); pk[3] = (short)f2b(e3);
        *(s16x4*)(Pw + cq * 128 + ((t4 * 32 + rg * 8) ^ ((cq & 7) << 4))) = pk;
      }
      if (qf) ls1 += sum; else ls0 += sum;
      pb[qf][0] = ld16(Pw + cq * 128 + ((rg * 16) ^ ((cq & 7) << 4)));
      pb[qf][1] = ld16(Pw + cq * 128 + ((64 + rg * 16) ^ ((cq & 7) << 4)));
    }

    // PV: O^T[d][q] += V^T_frag x P_frag
#pragma unroll
    for (int fd = 0; fd < 8; ++fd) {
      const int vrow = fd * 16 + cq;
      s16x8 va0 = ld16(Vb + vrow * 128 + ((rg * 16) ^ ((vrow & 7) << 4)));
      s16x8 va1 = ld16(Vb + vrow * 128 + ((64 + rg * 16) ^ ((vrow & 7) << 4)));
      acc[fd][0] = MFMA16(va0, pb[0][0], acc[fd][0]);
      acc[fd][0] = MFMA16(va1, pb[0][1], acc[fd][0]);
      acc[fd][1] = MFMA16(va0, pb[1][0], acc[fd][1]);
      acc[fd][1] = MFMA16(va1, pb[1][1], acc[fd][1]);
    }

    // T14 write-late: stage regs -> other buffer (its readers done at t-1)
    if (t < 31) {
      char* Kn = Ks + (cur ^ 1) * 16384;
      char* Vn = Vs + (cur ^ 1) * 16384;
#pragma unroll
      for (int j = 0; j < 2; ++j) {
        *(uint4*)(Kn + kds[j]) = sk[j];
        *(uint4*)(Vn + vds[j]) = sv[j];
      }
    }
    __syncthreads();
  }

  ls0 += __shfl_xor(ls0, 16); ls0 += __shfl_xor(ls0, 32);
  ls1 += __shfl_xor(ls1, 16); ls1 += __shfl_xor(ls1, 32);
  const float ri0 = 1.0f / ls0, ri1 = 1.0f / ls1;

  // O^T -> swizzled LDS transpose (reuse K/V area) -> coalesced global rows
  __syncthreads();
  char* Ow = lds + w * 8192;           // [32 q][256B]
#pragma unroll
  for (int fd = 0; fd < 8; ++fd)
#pragma unroll
    for (int qf = 0; qf < 2; ++qf) {
      const float ri = qf ? ri1 : ri0;
      const int ql = qf * 16 + cq;
#pragma unroll
      for (int rr = 0; rr < 4; rr += 2) {
        const unsigned int pk = (unsigned)f2b(acc[fd][qf][rr] * ri) |
                                ((unsigned)f2b(acc[fd][qf][rr + 1] * ri) << 16);
        const int d0 = fd * 16 + rg * 4 + rr;
        *(unsigned int*)(Ow + ql * 256 + ((d0 * 2) ^ ((ql & 7) << 4))) = pk;
      }
    }
  const int b = bh >> 3, h = bh & 7;
#pragma unroll
  for (int pr = 0; pr < 8; ++pr) {
    const int ql = pr * 4 + rg;
    uint4 ov = *(const uint4*)(Ow + ql * 256 + ((cq * 16) ^ ((ql & 7) << 4)));
    *(uint4*)((char*)Obuf + ((size_t)(b * LN + q0 + ql) * 1024 + h * 128) * 2 + cq * 16) = ov;
  }
}

// ---------------------------------------------------------------------------
extern "C" void kernel_launch(void* const* d_in, const int* in_sizes, int n_in,
                              void* d_out, int out_size, void* d_ws, size_t ws_size,
                              hipStream_t stream)
{
  (void)in_sizes; (void)n_in; (void)out_size; (void)ws_size;
  const float* q  = (const float*)d_in[0];
  const float* k  = (const float*)d_in[1];
  const float* v  = (const float*)d_in[2];
  const float* Wq = (const float*)d_in[3];
  const float* bq = (const float*)d_in[4];
  const float* Wk = (const float*)d_in[5];
  const float* bk = (const float*)d_in[6];
  const float* Wv = (const float*)d_in[7];
  const float* bv = (const float*)d_in[8];
  const float* Wo = (const float*)d_in[9];
  const float* bo = (const float*)d_in[10];

  char* ws = (char*)d_ws;
  size_t off = 0;
  auto alloc = [&](size_t bytes) { char* p = ws + off; off += (bytes + 255) & ~(size_t)255; return p; };
  __hip_bfloat16* qb  = (__hip_bfloat16*)alloc((size_t)MROWS * 128 * 2);
  __hip_bfloat16* kb  = (__hip_bfloat16*)alloc((size_t)MROWS * 128 * 2);
  __hip_bfloat16* vb  = (__hip_bfloat16*)alloc((size_t)MROWS * 128 * 2);
  __hip_bfloat16* Wqt = (__hip_bfloat16*)alloc(1024 * 128 * 2);
  __hip_bfloat16* Wkt = (__hip_bfloat16*)alloc(1024 * 128 * 2);
  __hip_bfloat16* Wvt = (__hip_bfloat16*)alloc(1024 * 128 * 2);
  __hip_bfloat16* Wot = (__hip_bfloat16*)alloc(128 * 1024 * 2);
  __hip_bfloat16* Qh  = (__hip_bfloat16*)alloc((size_t)64 * LN * 128 * 2);
  __hip_bfloat16* Kh  = (__hip_bfloat16*)alloc((size_t)64 * LN * 128 * 2);
  __hip_bfloat16* Vt  = (__hip_bfloat16*)alloc((size_t)64 * LN * 128 * 2);
  __hip_bfloat16* Ob  = (__hip_bfloat16*)alloc((size_t)MROWS * 1024 * 2);

  const float qscale = 1.4426950408889634f / sqrtf(128.0f);  // log2(e)/sqrt(dk)

  cast_kernel<<<8192, 256, 0, stream>>>(q, k, v, Wq, Wk, Wv, Wo,
                                        qb, kb, vb, Wqt, Wkt, Wvt, Wot, qscale);
  gemm_kernel<0><<<dim3(128, 8), 256, 0, stream>>>(qb, Wqt, bq, Qh, 128, qscale);
  gemm_kernel<0><<<dim3(128, 8), 256, 0, stream>>>(kb, Wkt, bk, Kh, 128, 1.0f);
  gemm_kernel<2><<<dim3(128, 8), 256, 0, stream>>>(vb, Wvt, bv, Vt, 128, 1.0f);
  attn_kernel<<<512, 512, 0, stream>>>(Qh, Kh, Vt, Ob);
  gemm_kernel<3><<<dim3(128, 1), 256, 0, stream>>>(Ob, Wot, bo, d_out, 1024, 1.0f);
}